// Round 1
// baseline (865.388 us; speedup 1.0000x reference)
//
#include <hip/hip_runtime.h>
#include <hip/hip_bf16.h>

#define NEG_SLOPE 0.2f

// ---------------- CSR build ----------------

__global__ void count_edges_k(const int* __restrict__ ei, int E, int n, int* __restrict__ cnt) {
    int e = blockIdx.x * 256 + threadIdx.x;
    int ET = E + n;
    if (e >= ET) return;
    int d = (e < E) ? ei[E + e] : (e - E);   // row 1 of edge_index = dst; self loops appended
    atomicAdd(&cnt[d], 1);
}

// each block scans 1024 counts -> local exclusive prefix + block sum
__global__ void scan1_k(const int* __restrict__ cnt, int* __restrict__ row_ptr,
                        int* __restrict__ bsums, int n) {
    __shared__ int sd[256];
    int b = blockIdx.x, t = threadIdx.x;
    int base = b * 1024 + t * 4;
    int v[4];
    int loc = 0;
#pragma unroll
    for (int j = 0; j < 4; ++j) {
        v[j] = (base + j < n) ? cnt[base + j] : 0;
        loc += v[j];
    }
    sd[t] = loc;
    __syncthreads();
    for (int off = 1; off < 256; off <<= 1) {
        int x = (t >= off) ? sd[t - off] : 0;
        __syncthreads();
        sd[t] += x;
        __syncthreads();
    }
    int run = sd[t] - loc;   // exclusive
    if (t == 255) bsums[b] = sd[t];
#pragma unroll
    for (int j = 0; j < 4; ++j) {
        if (base + j < n) row_ptr[base + j] = run;
        run += v[j];
    }
}

__global__ void scan2_k(int* __restrict__ bsums, int nb) {
    if (threadIdx.x == 0 && blockIdx.x == 0) {
        int run = 0;
        for (int i = 0; i < nb; ++i) { int x = bsums[i]; bsums[i] = run; run += x; }
    }
}

__global__ void scan3_k(int* __restrict__ row_ptr, int* __restrict__ pos,
                        const int* __restrict__ bsums, int n, int total) {
    int idx = blockIdx.x * 256 + threadIdx.x;
    if (idx < n) {
        int vv = row_ptr[idx] + bsums[idx >> 10];
        row_ptr[idx] = vv;
        pos[idx] = vv;
    } else if (idx == n) {
        row_ptr[n] = total;
    }
}

__global__ void scatter_edges_k(const int* __restrict__ ei, int E, int n,
                                int* __restrict__ pos, int* __restrict__ srcs) {
    int e = blockIdx.x * 256 + threadIdx.x;
    int ET = E + n;
    if (e >= ET) return;
    int s, d;
    if (e < E) { s = ei[e]; d = ei[E + e]; }
    else       { s = e - E; d = e - E; }
    int idx = atomicAdd(&pos[d], 1);
    srcs[idx] = s;
}

// ---------------- fp32 GEMM: C[M,Nc] = A[M,K] @ B[K,Nc] ----------------

#define BM 64
#define BN 64
#define BKK 16

__global__ __launch_bounds__(256) void sgemm_k(const float* __restrict__ A,
                                               const float* __restrict__ B,
                                               float* __restrict__ C,
                                               int M, int K, int Nc) {
    __shared__ float As[BKK][BM + 4];
    __shared__ float Bs[BKK][BN + 4];
    int bm = blockIdx.y * BM, bn = blockIdx.x * BN;
    int t = threadIdx.x;
    int tx = t & 15, ty = t >> 4;
    float acc[4][4] = {};
    for (int k0 = 0; k0 < K; k0 += BKK) {
        // A tile: 64 rows x 16 k, one float4 per thread
        {
            int row = t >> 2, kq = (t & 3) * 4;
            int r = bm + row;
            float4 v = make_float4(0.f, 0.f, 0.f, 0.f);
            if (r < M) v = *reinterpret_cast<const float4*>(A + (size_t)r * K + k0 + kq);
            As[kq + 0][row] = v.x; As[kq + 1][row] = v.y;
            As[kq + 2][row] = v.z; As[kq + 3][row] = v.w;
        }
        // B tile: 16 k x 64 n, one float4 per thread
        {
            int krow = t >> 4, nq = (t & 15) * 4;
            int col = bn + nq;
            float4 v = make_float4(0.f, 0.f, 0.f, 0.f);
            if (col < Nc) v = *reinterpret_cast<const float4*>(B + (size_t)(k0 + krow) * Nc + col);
            Bs[krow][nq + 0] = v.x; Bs[krow][nq + 1] = v.y;
            Bs[krow][nq + 2] = v.z; Bs[krow][nq + 3] = v.w;
        }
        __syncthreads();
#pragma unroll
        for (int k = 0; k < BKK; ++k) {
            float a[4], b[4];
#pragma unroll
            for (int i = 0; i < 4; ++i) a[i] = As[k][ty * 4 + i];
#pragma unroll
            for (int j = 0; j < 4; ++j) b[j] = Bs[k][tx * 4 + j];
#pragma unroll
            for (int i = 0; i < 4; ++i)
#pragma unroll
                for (int j = 0; j < 4; ++j)
                    acc[i][j] = fmaf(a[i], b[j], acc[i][j]);
        }
        __syncthreads();
    }
#pragma unroll
    for (int i = 0; i < 4; ++i) {
        int r = bm + ty * 4 + i;
        if (r >= M) continue;
#pragma unroll
        for (int j = 0; j < 4; ++j) {
            int c = bn + tx * 4 + j;
            if (c < Nc) C[(size_t)r * Nc + c] = acc[i][j];
        }
    }
}

// ---------------- attention logit precompute ----------------

// h: [N, 256] (8 heads x 32); a_src/a_dst: [8,32]; al_s/al_d: [N,8]
__global__ void compute_al_k(const float* __restrict__ h,
                             const float* __restrict__ a_src, const float* __restrict__ a_dst,
                             float* __restrict__ al_s, float* __restrict__ al_d, int n) {
    int node = blockIdx.x;
    int t = threadIdx.x;       // 0..255
    int hd = t >> 5, d = t & 31;
    float hv = h[(size_t)node * 256 + t];
    float ps = hv * a_src[t];
    float pd = hv * a_dst[t];
#pragma unroll
    for (int off = 16; off; off >>= 1) {
        ps += __shfl_xor(ps, off, 32);
        pd += __shfl_xor(pd, off, 32);
    }
    if (d == 0) {
        al_s[node * 8 + hd] = ps;
        al_d[node * 8 + hd] = pd;
    }
}

// layer 3: h [N,40], single head
__global__ void compute_al3_k(const float* __restrict__ h,
                              const float* __restrict__ a_src, const float* __restrict__ a_dst,
                              float* __restrict__ al_s, float* __restrict__ al_d, int n) {
    int wid = threadIdx.x >> 6, lane = threadIdx.x & 63;
    int node = blockIdx.x * 4 + wid;
    if (node >= n) return;
    float hv = (lane < 40) ? h[(size_t)node * 40 + lane] : 0.f;
    float ps = (lane < 40) ? hv * a_src[lane] : 0.f;
    float pd = (lane < 40) ? hv * a_dst[lane] : 0.f;
#pragma unroll
    for (int off = 32; off; off >>= 1) {
        ps += __shfl_xor(ps, off, 64);
        pd += __shfl_xor(pd, off, 64);
    }
    if (lane == 0) { al_s[node] = ps; al_d[node] = pd; }
}

// ---------------- softmax + aggregation ----------------

// one block (256 thr) per dst node; h [N,256]; out = ELU?(agg + bias)
template <bool ELU>
__global__ __launch_bounds__(256) void aggregate_k(const float* __restrict__ h,
                                                   const float* __restrict__ al_s,
                                                   const float* __restrict__ al_d,
                                                   const int* __restrict__ row_ptr,
                                                   const int* __restrict__ srcs,
                                                   const float* __restrict__ bias,
                                                   float* __restrict__ out, int n) {
    int dst = blockIdx.x;
    int t = threadIdx.x;
    int hd = t >> 5, d = t & 31;
    int beg = row_ptr[dst], end = row_ptr[dst + 1];
    float ald = al_d[dst * 8 + hd];
    // pass 1: per-head max (lanes of each head-group split the edges)
    float m = -1e30f;
    for (int i = beg + d; i < end; i += 32) {
        int s = srcs[i];
        float l = al_s[s * 8 + hd] + ald;
        l = (l > 0.f) ? l : NEG_SLOPE * l;
        m = fmaxf(m, l);
    }
#pragma unroll
    for (int off = 16; off; off >>= 1) m = fmaxf(m, __shfl_xor(m, off, 32));
    // pass 2: exp-weighted accumulate
    float acc = 0.f, sw = 0.f;
    for (int i = beg; i < end; ++i) {
        int s = srcs[i];
        float l = al_s[s * 8 + hd] + ald;
        l = (l > 0.f) ? l : NEG_SLOPE * l;
        float w = expf(l - m);
        sw += w;
        acc = fmaf(w, h[(size_t)s * 256 + t], acc);
    }
    float v = acc / (sw + 1e-16f) + bias[t];
    if (ELU) v = (v > 0.f) ? v : expm1f(v);
    out[(size_t)dst * 256 + t] = v;
}

// layer 3: one wave per dst node, 40 output dims, no ELU
__global__ __launch_bounds__(64) void aggregate3_k(const float* __restrict__ h,
                                                   const float* __restrict__ al_s,
                                                   const float* __restrict__ al_d,
                                                   const int* __restrict__ row_ptr,
                                                   const int* __restrict__ srcs,
                                                   const float* __restrict__ bias,
                                                   float* __restrict__ out, int n) {
    int dst = blockIdx.x;
    int lane = threadIdx.x;
    int beg = row_ptr[dst], end = row_ptr[dst + 1];
    float ald = al_d[dst];
    float m = -1e30f;
    for (int i = beg + lane; i < end; i += 64) {
        int s = srcs[i];
        float l = al_s[s] + ald;
        l = (l > 0.f) ? l : NEG_SLOPE * l;
        m = fmaxf(m, l);
    }
#pragma unroll
    for (int off = 32; off; off >>= 1) m = fmaxf(m, __shfl_xor(m, off, 64));
    float acc = 0.f, sw = 0.f;
    for (int i = beg; i < end; ++i) {
        int s = srcs[i];
        float l = al_s[s] + ald;
        l = (l > 0.f) ? l : NEG_SLOPE * l;
        float w = expf(l - m);
        sw += w;
        if (lane < 40) acc = fmaf(w, h[(size_t)s * 40 + lane], acc);
    }
    if (lane < 40) out[(size_t)dst * 40 + lane] = acc / (sw + 1e-16f) + bias[lane];
}

// ---------------- launch ----------------

extern "C" void kernel_launch(void* const* d_in, const int* in_sizes, int n_in,
                              void* d_out, int out_size, void* d_ws, size_t ws_size,
                              hipStream_t stream) {
    const float* x   = (const float*)d_in[0];
    const int*   ei  = (const int*)d_in[1];
    const float* W1  = (const float*)d_in[2];
    const float* as1 = (const float*)d_in[3];
    const float* ad1 = (const float*)d_in[4];
    const float* b1  = (const float*)d_in[5];
    const float* W2  = (const float*)d_in[6];
    const float* as2 = (const float*)d_in[7];
    const float* ad2 = (const float*)d_in[8];
    const float* b2  = (const float*)d_in[9];
    const float* W3  = (const float*)d_in[10];
    const float* as3 = (const float*)d_in[11];
    const float* ad3 = (const float*)d_in[12];
    const float* b3  = (const float*)d_in[13];

    const int N = in_sizes[0] / 128;   // 50000
    const int E = in_sizes[1] / 2;     // 800000
    const int ET = E + N;

    char* ws = (char*)d_ws;
    size_t off = 0;
    auto alloc = [&](size_t bytes) -> void* {
        void* p = ws + off;
        off += (bytes + 255) & ~(size_t)255;
        return p;
    };
    int*   row_ptr = (int*)alloc(sizeof(int) * (N + 1));
    int*   pos     = (int*)alloc(sizeof(int) * N);        // doubles as counts
    int*   srcs    = (int*)alloc(sizeof(int) * ET);
    int*   bsums   = (int*)alloc(sizeof(int) * 64);
    float* als     = (float*)alloc(sizeof(float) * N * 8);
    float* ald     = (float*)alloc(sizeof(float) * N * 8);
    float* hbuf    = (float*)alloc(sizeof(float) * (size_t)N * 256);
    float* obuf    = (float*)alloc(sizeof(float) * (size_t)N * 256);
    (void)ws_size;

    const int nb = (N + 1023) / 1024;

    // --- CSR build (dst is identical for all 3 layers) ---
    hipMemsetAsync(pos, 0, sizeof(int) * N, stream);
    count_edges_k<<<(ET + 255) / 256, 256, 0, stream>>>(ei, E, N, pos);
    scan1_k<<<nb, 256, 0, stream>>>(pos, row_ptr, bsums, N);
    scan2_k<<<1, 64, 0, stream>>>(bsums, nb);
    scan3_k<<<(N + 1 + 255) / 256, 256, 0, stream>>>(row_ptr, pos, bsums, N, ET);
    scatter_edges_k<<<(ET + 255) / 256, 256, 0, stream>>>(ei, E, N, pos, srcs);

    dim3 g1(4, (N + BM - 1) / BM);

    // --- layer 1: x[ N,128 ] @ W1[128,256] ---
    sgemm_k<<<g1, 256, 0, stream>>>(x, W1, hbuf, N, 128, 256);
    compute_al_k<<<N, 256, 0, stream>>>(hbuf, as1, ad1, als, ald, N);
    aggregate_k<true><<<N, 256, 0, stream>>>(hbuf, als, ald, row_ptr, srcs, b1, obuf, N);

    // --- layer 2: obuf[N,256] @ W2[256,256] ---
    sgemm_k<<<g1, 256, 0, stream>>>(obuf, W2, hbuf, N, 256, 256);
    compute_al_k<<<N, 256, 0, stream>>>(hbuf, as2, ad2, als, ald, N);
    aggregate_k<true><<<N, 256, 0, stream>>>(hbuf, als, ald, row_ptr, srcs, b2, obuf, N);

    // --- layer 3: obuf[N,256] @ W3[256,40], 1 head, no ELU ---
    sgemm_k<<<dim3(1, (N + BM - 1) / BM), 256, 0, stream>>>(obuf, W3, hbuf, N, 256, 40);
    compute_al3_k<<<(N + 3) / 4, 256, 0, stream>>>(hbuf, as3, ad3, als, ald, N);
    aggregate3_k<<<N, 64, 0, stream>>>(hbuf, als, ald, row_ptr, srcs, b3, (float*)d_out, N);
}

// Round 2
// 675.994 us; speedup vs baseline: 1.2802x; 1.2802x over previous
//
#include <hip/hip_runtime.h>
#include <hip/hip_bf16.h>

#define NEG_SLOPE 0.2f

// ---------------- CSR build ----------------

__global__ void count_edges_k(const int* __restrict__ ei, int E, int n, int* __restrict__ cnt) {
    int e = blockIdx.x * 256 + threadIdx.x;
    int ET = E + n;
    if (e >= ET) return;
    int d = (e < E) ? ei[E + e] : (e - E);   // row 1 of edge_index = dst; self loops appended
    atomicAdd(&cnt[d], 1);
}

__global__ void scan1_k(const int* __restrict__ cnt, int* __restrict__ row_ptr,
                        int* __restrict__ bsums, int n) {
    __shared__ int sd[256];
    int b = blockIdx.x, t = threadIdx.x;
    int base = b * 1024 + t * 4;
    int v[4];
    int loc = 0;
#pragma unroll
    for (int j = 0; j < 4; ++j) {
        v[j] = (base + j < n) ? cnt[base + j] : 0;
        loc += v[j];
    }
    sd[t] = loc;
    __syncthreads();
    for (int off = 1; off < 256; off <<= 1) {
        int x = (t >= off) ? sd[t - off] : 0;
        __syncthreads();
        sd[t] += x;
        __syncthreads();
    }
    int run = sd[t] - loc;   // exclusive
    if (t == 255) bsums[b] = sd[t];
#pragma unroll
    for (int j = 0; j < 4; ++j) {
        if (base + j < n) row_ptr[base + j] = run;
        run += v[j];
    }
}

__global__ void scan2_k(int* __restrict__ bsums, int nb) {
    if (threadIdx.x == 0 && blockIdx.x == 0) {
        int run = 0;
        for (int i = 0; i < nb; ++i) { int x = bsums[i]; bsums[i] = run; run += x; }
    }
}

__global__ void scan3_k(int* __restrict__ row_ptr, int* __restrict__ pos,
                        const int* __restrict__ bsums, int n, int total) {
    int idx = blockIdx.x * 256 + threadIdx.x;
    if (idx < n) {
        int vv = row_ptr[idx] + bsums[idx >> 10];
        row_ptr[idx] = vv;
        pos[idx] = vv;
    } else if (idx == n) {
        row_ptr[n] = total;
    }
}

__global__ void scatter_edges_k(const int* __restrict__ ei, int E, int n,
                                int* __restrict__ pos, int* __restrict__ srcs) {
    int e = blockIdx.x * 256 + threadIdx.x;
    int ET = E + n;
    if (e >= ET) return;
    int s, d;
    if (e < E) { s = ei[e]; d = ei[E + e]; }
    else       { s = e - E; d = e - E; }
    int idx = atomicAdd(&pos[d], 1);
    srcs[idx] = s;
}

// ---------------- fp32 GEMM: C[M,Nc] = A[M,K] @ B[K,Nc] ----------------

#define BM 64
#define BN 64
#define BKK 16

__global__ __launch_bounds__(256) void sgemm_k(const float* __restrict__ A,
                                               const float* __restrict__ B,
                                               float* __restrict__ C,
                                               int M, int K, int Nc) {
    __shared__ float As[BKK][BM + 4];
    __shared__ float Bs[BKK][BN + 4];
    int bm = blockIdx.y * BM, bn = blockIdx.x * BN;
    int t = threadIdx.x;
    int tx = t & 15, ty = t >> 4;
    float acc[4][4] = {};
    for (int k0 = 0; k0 < K; k0 += BKK) {
        {
            int row = t >> 2, kq = (t & 3) * 4;
            int r = bm + row;
            float4 v = make_float4(0.f, 0.f, 0.f, 0.f);
            if (r < M) v = *reinterpret_cast<const float4*>(A + (size_t)r * K + k0 + kq);
            As[kq + 0][row] = v.x; As[kq + 1][row] = v.y;
            As[kq + 2][row] = v.z; As[kq + 3][row] = v.w;
        }
        {
            int krow = t >> 4, nq = (t & 15) * 4;
            int col = bn + nq;
            float4 v = make_float4(0.f, 0.f, 0.f, 0.f);
            if (col < Nc) v = *reinterpret_cast<const float4*>(B + (size_t)(k0 + krow) * Nc + col);
            Bs[krow][nq + 0] = v.x; Bs[krow][nq + 1] = v.y;
            Bs[krow][nq + 2] = v.z; Bs[krow][nq + 3] = v.w;
        }
        __syncthreads();
#pragma unroll
        for (int k = 0; k < BKK; ++k) {
            float a[4], b[4];
#pragma unroll
            for (int i = 0; i < 4; ++i) a[i] = As[k][ty * 4 + i];
#pragma unroll
            for (int j = 0; j < 4; ++j) b[j] = Bs[k][tx * 4 + j];
#pragma unroll
            for (int i = 0; i < 4; ++i)
#pragma unroll
                for (int j = 0; j < 4; ++j)
                    acc[i][j] = fmaf(a[i], b[j], acc[i][j]);
        }
        __syncthreads();
    }
#pragma unroll
    for (int i = 0; i < 4; ++i) {
        int r = bm + ty * 4 + i;
        if (r >= M) continue;
#pragma unroll
        for (int j = 0; j < 4; ++j) {
            int c = bn + tx * 4 + j;
            if (c < Nc) C[(size_t)r * Nc + c] = acc[i][j];
        }
    }
}

// ---------------- attention logit precompute ----------------

__global__ void compute_al_k(const float* __restrict__ h,
                             const float* __restrict__ a_src, const float* __restrict__ a_dst,
                             float* __restrict__ al_s, float* __restrict__ al_d, int n) {
    int node = blockIdx.x;
    int t = threadIdx.x;
    int hd = t >> 5, d = t & 31;
    float hv = h[(size_t)node * 256 + t];
    float ps = hv * a_src[t];
    float pd = hv * a_dst[t];
#pragma unroll
    for (int off = 16; off; off >>= 1) {
        ps += __shfl_xor(ps, off, 32);
        pd += __shfl_xor(pd, off, 32);
    }
    if (d == 0) {
        al_s[node * 8 + hd] = ps;
        al_d[node * 8 + hd] = pd;
    }
}

__global__ void compute_al3_k(const float* __restrict__ h,
                              const float* __restrict__ a_src, const float* __restrict__ a_dst,
                              float* __restrict__ al_s, float* __restrict__ al_d, int n) {
    int wid = threadIdx.x >> 6, lane = threadIdx.x & 63;
    int node = blockIdx.x * 4 + wid;
    if (node >= n) return;
    float hv = (lane < 40) ? h[(size_t)node * 40 + lane] : 0.f;
    float ps = (lane < 40) ? hv * a_src[lane] : 0.f;
    float pd = (lane < 40) ? hv * a_dst[lane] : 0.f;
#pragma unroll
    for (int off = 32; off; off >>= 1) {
        ps += __shfl_xor(ps, off, 64);
        pd += __shfl_xor(pd, off, 64);
    }
    if (lane == 0) { al_s[node] = ps; al_d[node] = pd; }
}

// ---------------- softmax + aggregation (cooperative, 1x exp redundancy) ----------------

#define CH 64

// one block (256 thr) per dst node; h [N,256]; out = ELU?(agg/sum + bias)
template <bool ELU>
__global__ __launch_bounds__(256) void gat_aggregate_k(const float* __restrict__ h,
                                                       const float* __restrict__ al_s,
                                                       const float* __restrict__ al_d,
                                                       const int* __restrict__ row_ptr,
                                                       const int* __restrict__ srcs,
                                                       const float* __restrict__ bias,
                                                       float* __restrict__ out, int n) {
    __shared__ float w_lds[CH][8];
    __shared__ int   sc[CH];
    __shared__ float red[256];
    __shared__ float part[4][256];
    __shared__ float m_sh[8], inv_sh[8], ald_sh[8];

    int dst = blockIdx.x;
    int t = threadIdx.x;
    int beg = row_ptr[dst], end = row_ptr[dst + 1];
    int deg = end - beg;

    if (t < 8) ald_sh[t] = al_d[dst * 8 + t];
    __syncthreads();

    int hh = t & 7, e0 = t >> 3;   // pass-1 / phase-A role: head hh, edge-offset e0 (0..31)
    float aldv = ald_sh[hh];

    // ---- pass 1: per-head max over all edges (1x redundancy) ----
    float mp = -1e30f;
    for (int e = e0; e < deg; e += 32) {
        int s = srcs[beg + e];
        float l = al_s[s * 8 + hh] + aldv;
        l = (l > 0.f) ? l : NEG_SLOPE * l;
        mp = fmaxf(mp, l);
    }
    red[t] = mp;
    __syncthreads();
#pragma unroll
    for (int off = 128; off >= 8; off >>= 1) {
        if (t < off) red[t] = fmaxf(red[t], red[t + off]);
        __syncthreads();
    }
    if (t < 8) m_sh[t] = red[t];
    __syncthreads();
    float mh = m_sh[hh];

    // ---- chunked: phase A (compute w once per edge-head), phase B (float4 gather-accum) ----
    int g = t >> 6, lane = t & 63;       // phase-B role: edge-group g, column block lane
    int hd = lane >> 3;                  // head of columns 4*lane..4*lane+3
    float4 acc = make_float4(0.f, 0.f, 0.f, 0.f);
    float swp = 0.f;

    for (int c0 = 0; c0 < deg; c0 += CH) {
        int len = min(CH, deg - c0);
        // phase A: slots e' in {e0, e0+32}, head hh
#pragma unroll
        for (int sl = 0; sl < 2; ++sl) {
            int ep = e0 + sl * 32;
            if (ep < len) {
                int s = srcs[beg + c0 + ep];
                if (hh == 0) sc[ep] = s;
                float l = al_s[s * 8 + hh] + aldv;
                l = (l > 0.f) ? l : NEG_SLOPE * l;
                float w = expf(l - mh);
                w_lds[ep][hh] = w;
                swp += w;
            }
        }
        __syncthreads();
        // phase B: group g handles edges g, g+4, ... ; 4 cols per thread
        for (int e = g; e < len; e += 4) {
            float w = w_lds[e][hd];
            const float4* hp = reinterpret_cast<const float4*>(h + (size_t)sc[e] * 256);
            float4 v = hp[lane];
            acc.x = fmaf(w, v.x, acc.x);
            acc.y = fmaf(w, v.y, acc.y);
            acc.z = fmaf(w, v.z, acc.z);
            acc.w = fmaf(w, v.w, acc.w);
        }
        __syncthreads();
    }

    // ---- softmax denominator reduce ----
    red[t] = swp;
    __syncthreads();
#pragma unroll
    for (int off = 128; off >= 8; off >>= 1) {
        if (t < off) red[t] += red[t + off];
        __syncthreads();
    }
    if (t < 8) inv_sh[t] = 1.f / (red[t] + 1e-16f);
    // ---- cross-group partial reduce ----
    *reinterpret_cast<float4*>(&part[g][4 * lane]) = acc;
    __syncthreads();
    float tot = part[0][t] + part[1][t] + part[2][t] + part[3][t];
    float v = tot * inv_sh[t >> 5] + bias[t];
    if (ELU) v = (v > 0.f) ? v : expm1f(v);
    out[(size_t)dst * 256 + t] = v;
}

// layer 3: one wave per dst node, 40 output dims, 1 head, no ELU
__global__ __launch_bounds__(64) void gat_aggregate3_k(const float* __restrict__ h,
                                                       const float* __restrict__ al_s,
                                                       const float* __restrict__ al_d,
                                                       const int* __restrict__ row_ptr,
                                                       const int* __restrict__ srcs,
                                                       const float* __restrict__ bias,
                                                       float* __restrict__ out, int n) {
    __shared__ float w_l[CH];
    __shared__ int   sc[CH];
    int dst = blockIdx.x;
    int lane = threadIdx.x;
    int beg = row_ptr[dst], end = row_ptr[dst + 1];
    int deg = end - beg;
    float ald = al_d[dst];

    float mp = -1e30f;
    for (int e = lane; e < deg; e += 64) {
        int s = srcs[beg + e];
        float l = al_s[s] + ald;
        l = (l > 0.f) ? l : NEG_SLOPE * l;
        mp = fmaxf(mp, l);
    }
#pragma unroll
    for (int off = 32; off; off >>= 1) mp = fmaxf(mp, __shfl_xor(mp, off, 64));

    float acc = 0.f, swp = 0.f;
    for (int c0 = 0; c0 < deg; c0 += CH) {
        int len = min(CH, deg - c0);
        if (lane < len) {
            int s = srcs[beg + c0 + lane];
            sc[lane] = s;
            float l = al_s[s] + ald;
            l = (l > 0.f) ? l : NEG_SLOPE * l;
            float w = expf(l - mp);
            w_l[lane] = w;
            swp += w;
        }
        __syncthreads();
        if (lane < 40) {
            for (int e = 0; e < len; ++e)
                acc = fmaf(w_l[e], h[(size_t)sc[e] * 40 + lane], acc);
        }
        __syncthreads();
    }
#pragma unroll
    for (int off = 32; off; off >>= 1) swp += __shfl_xor(swp, off, 64);
    if (lane < 40) out[(size_t)dst * 40 + lane] = acc / (swp + 1e-16f) + bias[lane];
}

// ---------------- launch ----------------

extern "C" void kernel_launch(void* const* d_in, const int* in_sizes, int n_in,
                              void* d_out, int out_size, void* d_ws, size_t ws_size,
                              hipStream_t stream) {
    const float* x   = (const float*)d_in[0];
    const int*   ei  = (const int*)d_in[1];
    const float* W1  = (const float*)d_in[2];
    const float* as1 = (const float*)d_in[3];
    const float* ad1 = (const float*)d_in[4];
    const float* b1  = (const float*)d_in[5];
    const float* W2  = (const float*)d_in[6];
    const float* as2 = (const float*)d_in[7];
    const float* ad2 = (const float*)d_in[8];
    const float* b2  = (const float*)d_in[9];
    const float* W3  = (const float*)d_in[10];
    const float* as3 = (const float*)d_in[11];
    const float* ad3 = (const float*)d_in[12];
    const float* b3  = (const float*)d_in[13];

    const int N = in_sizes[0] / 128;   // 50000
    const int E = in_sizes[1] / 2;     // 800000
    const int ET = E + N;

    char* ws = (char*)d_ws;
    size_t off = 0;
    auto alloc = [&](size_t bytes) -> void* {
        void* p = ws + off;
        off += (bytes + 255) & ~(size_t)255;
        return p;
    };
    int*   row_ptr = (int*)alloc(sizeof(int) * (N + 1));
    int*   pos     = (int*)alloc(sizeof(int) * N);
    int*   srcs    = (int*)alloc(sizeof(int) * ET);
    int*   bsums   = (int*)alloc(sizeof(int) * 64);
    float* als     = (float*)alloc(sizeof(float) * N * 8);
    float* ald     = (float*)alloc(sizeof(float) * N * 8);
    float* hbuf    = (float*)alloc(sizeof(float) * (size_t)N * 256);
    float* obuf    = (float*)alloc(sizeof(float) * (size_t)N * 256);
    (void)ws_size;

    const int nb = (N + 1023) / 1024;

    // --- CSR build (dst is identical for all 3 layers) ---
    hipMemsetAsync(pos, 0, sizeof(int) * N, stream);
    count_edges_k<<<(ET + 255) / 256, 256, 0, stream>>>(ei, E, N, pos);
    scan1_k<<<nb, 256, 0, stream>>>(pos, row_ptr, bsums, N);
    scan2_k<<<1, 64, 0, stream>>>(bsums, nb);
    scan3_k<<<(N + 1 + 255) / 256, 256, 0, stream>>>(row_ptr, pos, bsums, N, ET);
    scatter_edges_k<<<(ET + 255) / 256, 256, 0, stream>>>(ei, E, N, pos, srcs);

    dim3 g1(4, (N + BM - 1) / BM);

    // --- layer 1 ---
    sgemm_k<<<g1, 256, 0, stream>>>(x, W1, hbuf, N, 128, 256);
    compute_al_k<<<N, 256, 0, stream>>>(hbuf, as1, ad1, als, ald, N);
    gat_aggregate_k<true><<<N, 256, 0, stream>>>(hbuf, als, ald, row_ptr, srcs, b1, obuf, N);

    // --- layer 2 ---
    sgemm_k<<<g1, 256, 0, stream>>>(obuf, W2, hbuf, N, 256, 256);
    compute_al_k<<<N, 256, 0, stream>>>(hbuf, as2, ad2, als, ald, N);
    gat_aggregate_k<true><<<N, 256, 0, stream>>>(hbuf, als, ald, row_ptr, srcs, b2, obuf, N);

    // --- layer 3 ---
    sgemm_k<<<dim3(1, (N + BM - 1) / BM), 256, 0, stream>>>(obuf, W3, hbuf, N, 256, 40);
    compute_al3_k<<<(N + 3) / 4, 256, 0, stream>>>(hbuf, as3, ad3, als, ald, N);
    gat_aggregate3_k<<<N, 64, 0, stream>>>(hbuf, als, ald, row_ptr, srcs, b3, (float*)d_out, N);
}

// Round 3
// 594.472 us; speedup vs baseline: 1.4557x; 1.1371x over previous
//
#include <hip/hip_runtime.h>
#include <hip/hip_bf16.h>

#define NEG_SLOPE 0.2f

typedef __attribute__((ext_vector_type(8))) short bf16x8;
typedef __attribute__((ext_vector_type(4))) float f32x4;

__device__ __forceinline__ unsigned short f2bf(float v) {
    union { float f; unsigned int u; } x; x.f = v;
    unsigned int r = x.u + 0x7fffu + ((x.u >> 16) & 1u);
    return (unsigned short)(r >> 16);
}
__device__ __forceinline__ float bf2f(unsigned short b) {
    union { unsigned int u; float f; } x; x.u = ((unsigned int)b) << 16;
    return x.f;
}

// ---------------- CSR build ----------------

__global__ void count_edges_k(const int* __restrict__ ei, int E, int n, int* __restrict__ cnt) {
    int e = blockIdx.x * 256 + threadIdx.x;
    int ET = E + n;
    if (e >= ET) return;
    int d = (e < E) ? ei[E + e] : (e - E);
    atomicAdd(&cnt[d], 1);
}

__global__ void scan1_k(const int* __restrict__ cnt, int* __restrict__ row_ptr,
                        int* __restrict__ bsums, int n) {
    __shared__ int sd[256];
    int b = blockIdx.x, t = threadIdx.x;
    int base = b * 1024 + t * 4;
    int v[4];
    int loc = 0;
#pragma unroll
    for (int j = 0; j < 4; ++j) {
        v[j] = (base + j < n) ? cnt[base + j] : 0;
        loc += v[j];
    }
    sd[t] = loc;
    __syncthreads();
    for (int off = 1; off < 256; off <<= 1) {
        int x = (t >= off) ? sd[t - off] : 0;
        __syncthreads();
        sd[t] += x;
        __syncthreads();
    }
    int run = sd[t] - loc;
    if (t == 255) bsums[b] = sd[t];
#pragma unroll
    for (int j = 0; j < 4; ++j) {
        if (base + j < n) row_ptr[base + j] = run;
        run += v[j];
    }
}

__global__ void scan2_k(int* __restrict__ bsums, int nb) {
    if (threadIdx.x == 0 && blockIdx.x == 0) {
        int run = 0;
        for (int i = 0; i < nb; ++i) { int x = bsums[i]; bsums[i] = run; run += x; }
    }
}

__global__ void scan3_k(int* __restrict__ row_ptr, int* __restrict__ pos,
                        const int* __restrict__ bsums, int n, int total) {
    int idx = blockIdx.x * 256 + threadIdx.x;
    if (idx < n) {
        int vv = row_ptr[idx] + bsums[idx >> 10];
        row_ptr[idx] = vv;
        pos[idx] = vv;
    } else if (idx == n) {
        row_ptr[n] = total;
    }
}

__global__ void scatter_edges_k(const int* __restrict__ ei, int E, int n,
                                int* __restrict__ pos, int* __restrict__ srcs) {
    int e = blockIdx.x * 256 + threadIdx.x;
    int ET = E + n;
    if (e >= ET) return;
    int s, d;
    if (e < E) { s = ei[e]; d = ei[E + e]; }
    else       { s = e - E; d = e - E; }
    int idx = atomicAdd(&pos[d], 1);
    srcs[idx] = s;
}

// ---------------- weight pre-convert: W[K][Nc] fp32 -> col-major hi/lo bf16 [Nc][K] ----------------

__global__ void convert_w_k(const float* __restrict__ W,
                            unsigned short* __restrict__ Bh, unsigned short* __restrict__ Bl,
                            int K, int Nc) {
    int idx = blockIdx.x * 256 + threadIdx.x;
    if (idx >= K * Nc) return;
    int k = idx / Nc, c = idx - k * Nc;
    float v = W[idx];
    unsigned short h = f2bf(v);
    float r = v - bf2f(h);
    Bh[c * K + k] = h;
    Bl[c * K + k] = f2bf(r);
}

// ---------------- split-bf16 MFMA GEMM: C[M,Nc] = A[M,K] @ W, Nc%128==0, K%32==0 ----------------
// A fp32 row-major; W pre-converted to Bh/Bl bf16 col-major [Nc][K].
// block = 256 thr (4 waves), tile 128x128, wave tile 64x64, K-step 32.

#define GPAD 40   // LDS row stride in bf16 elements (32 + 8 pad)

__global__ __launch_bounds__(256) void mfma_gemm_k(const float* __restrict__ A,
                                                   const unsigned short* __restrict__ Bh,
                                                   const unsigned short* __restrict__ Bl,
                                                   float* __restrict__ C,
                                                   int M, int K, int Nc) {
    __shared__ unsigned short Ash[128][GPAD];
    __shared__ unsigned short Asl[128][GPAD];
    __shared__ unsigned short Bsh[128][GPAD];
    __shared__ unsigned short Bsl[128][GPAD];

    int bm = blockIdx.y * 128;
    int bn = blockIdx.x * 128;
    int t = threadIdx.x;
    int w = t >> 6, l = t & 63;
    int wm = w >> 1, wn = w & 1;
    int lr = l & 15, lk = (l >> 4) * 8;    // fragment row/col and k-offset

    // staging roles
    int srow = t >> 1;              // 0..127
    int skh  = (t & 1) * 16;        // 0 or 16

    f32x4 acc[4][4];
#pragma unroll
    for (int i = 0; i < 4; ++i)
#pragma unroll
        for (int j = 0; j < 4; ++j)
            acc[i][j] = (f32x4){0.f, 0.f, 0.f, 0.f};

    const int arow = bm + srow;
    const bool arow_ok = (arow < M);
    const size_t acol_base = (size_t)arow * K + skh;
    const size_t bcol_base = (size_t)(bn + srow) * K + skh;

    for (int k0 = 0; k0 < K; k0 += 32) {
        // ---- stage A (fp32 -> hi/lo bf16) ----
        float vv[16];
        if (arow_ok) {
            const float4* ap = reinterpret_cast<const float4*>(A + acol_base + k0);
#pragma unroll
            for (int q = 0; q < 4; ++q) {
                float4 v4 = ap[q];
                vv[4 * q + 0] = v4.x; vv[4 * q + 1] = v4.y;
                vv[4 * q + 2] = v4.z; vv[4 * q + 3] = v4.w;
            }
        } else {
#pragma unroll
            for (int q = 0; q < 16; ++q) vv[q] = 0.f;
        }
        unsigned int hw[8], lw[8];
#pragma unroll
        for (int q = 0; q < 8; ++q) {
            unsigned short h0 = f2bf(vv[2 * q]);
            unsigned short h1 = f2bf(vv[2 * q + 1]);
            unsigned short l0 = f2bf(vv[2 * q] - bf2f(h0));
            unsigned short l1 = f2bf(vv[2 * q + 1] - bf2f(h1));
            hw[q] = (unsigned int)h0 | ((unsigned int)h1 << 16);
            lw[q] = (unsigned int)l0 | ((unsigned int)l1 << 16);
        }
        __syncthreads();   // protect previous iteration's reads
        {
            uint4* dh = reinterpret_cast<uint4*>(&Ash[srow][skh]);
            uint4* dl = reinterpret_cast<uint4*>(&Asl[srow][skh]);
            dh[0] = make_uint4(hw[0], hw[1], hw[2], hw[3]);
            dh[1] = make_uint4(hw[4], hw[5], hw[6], hw[7]);
            dl[0] = make_uint4(lw[0], lw[1], lw[2], lw[3]);
            dl[1] = make_uint4(lw[4], lw[5], lw[6], lw[7]);
        }
        // ---- stage B (pre-converted, straight copy) ----
        {
            const uint4* sh = reinterpret_cast<const uint4*>(Bh + bcol_base + k0);
            const uint4* sl = reinterpret_cast<const uint4*>(Bl + bcol_base + k0);
            uint4* dh = reinterpret_cast<uint4*>(&Bsh[srow][skh]);
            uint4* dl = reinterpret_cast<uint4*>(&Bsl[srow][skh]);
            dh[0] = sh[0]; dh[1] = sh[1];
            dl[0] = sl[0]; dl[1] = sl[1];
        }
        __syncthreads();

        // ---- fragments + MFMA ----
        bf16x8 ah[4], al[4], bh[4], bl[4];
#pragma unroll
        for (int i = 0; i < 4; ++i) {
            int r = wm * 64 + i * 16 + lr;
            ah[i] = *reinterpret_cast<const bf16x8*>(&Ash[r][lk]);
            al[i] = *reinterpret_cast<const bf16x8*>(&Asl[r][lk]);
        }
#pragma unroll
        for (int j = 0; j < 4; ++j) {
            int c = wn * 64 + j * 16 + lr;
            bh[j] = *reinterpret_cast<const bf16x8*>(&Bsh[c][lk]);
            bl[j] = *reinterpret_cast<const bf16x8*>(&Bsl[c][lk]);
        }
#pragma unroll
        for (int i = 0; i < 4; ++i)
#pragma unroll
            for (int j = 0; j < 4; ++j) {
                acc[i][j] = __builtin_amdgcn_mfma_f32_16x16x32_bf16(ah[i], bh[j], acc[i][j], 0, 0, 0);
                acc[i][j] = __builtin_amdgcn_mfma_f32_16x16x32_bf16(ah[i], bl[j], acc[i][j], 0, 0, 0);
                acc[i][j] = __builtin_amdgcn_mfma_f32_16x16x32_bf16(al[i], bh[j], acc[i][j], 0, 0, 0);
            }
    }

    // ---- epilogue: D mapping col = lane&15, row = (lane>>4)*4 + reg ----
#pragma unroll
    for (int i = 0; i < 4; ++i) {
#pragma unroll
        for (int r = 0; r < 4; ++r) {
            int row_g = bm + wm * 64 + i * 16 + (l >> 4) * 4 + r;
            if (row_g >= M) continue;
#pragma unroll
            for (int j = 0; j < 4; ++j) {
                int col_g = bn + wn * 64 + j * 16 + lr;
                C[(size_t)row_g * Nc + col_g] = acc[i][j][r];
            }
        }
    }
}

// ---------------- fp32 GEMM (layer 3 only, Nc=40) ----------------

#define BM 64
#define BN 64
#define BKK 16

__global__ __launch_bounds__(256) void sgemm_k(const float* __restrict__ A,
                                               const float* __restrict__ B,
                                               float* __restrict__ C,
                                               int M, int K, int Nc) {
    __shared__ float As[BKK][BM + 4];
    __shared__ float Bs[BKK][BN + 4];
    int bm = blockIdx.y * BM, bn = blockIdx.x * BN;
    int t = threadIdx.x;
    int tx = t & 15, ty = t >> 4;
    float acc[4][4] = {};
    for (int k0 = 0; k0 < K; k0 += BKK) {
        {
            int row = t >> 2, kq = (t & 3) * 4;
            int r = bm + row;
            float4 v = make_float4(0.f, 0.f, 0.f, 0.f);
            if (r < M) v = *reinterpret_cast<const float4*>(A + (size_t)r * K + k0 + kq);
            As[kq + 0][row] = v.x; As[kq + 1][row] = v.y;
            As[kq + 2][row] = v.z; As[kq + 3][row] = v.w;
        }
        {
            int krow = t >> 4, nq = (t & 15) * 4;
            int col = bn + nq;
            float4 v = make_float4(0.f, 0.f, 0.f, 0.f);
            if (col < Nc) v = *reinterpret_cast<const float4*>(B + (size_t)(k0 + krow) * Nc + col);
            Bs[krow][nq + 0] = v.x; Bs[krow][nq + 1] = v.y;
            Bs[krow][nq + 2] = v.z; Bs[krow][nq + 3] = v.w;
        }
        __syncthreads();
#pragma unroll
        for (int k = 0; k < BKK; ++k) {
            float a[4], b[4];
#pragma unroll
            for (int i = 0; i < 4; ++i) a[i] = As[k][ty * 4 + i];
#pragma unroll
            for (int j = 0; j < 4; ++j) b[j] = Bs[k][tx * 4 + j];
#pragma unroll
            for (int i = 0; i < 4; ++i)
#pragma unroll
                for (int j = 0; j < 4; ++j)
                    acc[i][j] = fmaf(a[i], b[j], acc[i][j]);
        }
        __syncthreads();
    }
#pragma unroll
    for (int i = 0; i < 4; ++i) {
        int r = bm + ty * 4 + i;
        if (r >= M) continue;
#pragma unroll
        for (int j = 0; j < 4; ++j) {
            int c = bn + tx * 4 + j;
            if (c < Nc) C[(size_t)r * Nc + c] = acc[i][j];
        }
    }
}

// ---------------- attention logit precompute ----------------

__global__ void compute_al_k(const float* __restrict__ h,
                             const float* __restrict__ a_src, const float* __restrict__ a_dst,
                             float* __restrict__ al_s, float* __restrict__ al_d, int n) {
    int node = blockIdx.x;
    int t = threadIdx.x;
    int hd = t >> 5, d = t & 31;
    float hv = h[(size_t)node * 256 + t];
    float ps = hv * a_src[t];
    float pd = hv * a_dst[t];
#pragma unroll
    for (int off = 16; off; off >>= 1) {
        ps += __shfl_xor(ps, off, 32);
        pd += __shfl_xor(pd, off, 32);
    }
    if (d == 0) {
        al_s[node * 8 + hd] = ps;
        al_d[node * 8 + hd] = pd;
    }
}

__global__ void compute_al3_k(const float* __restrict__ h,
                              const float* __restrict__ a_src, const float* __restrict__ a_dst,
                              float* __restrict__ al_s, float* __restrict__ al_d, int n) {
    int wid = threadIdx.x >> 6, lane = threadIdx.x & 63;
    int node = blockIdx.x * 4 + wid;
    if (node >= n) return;
    float hv = (lane < 40) ? h[(size_t)node * 40 + lane] : 0.f;
    float ps = (lane < 40) ? hv * a_src[lane] : 0.f;
    float pd = (lane < 40) ? hv * a_dst[lane] : 0.f;
#pragma unroll
    for (int off = 32; off; off >>= 1) {
        ps += __shfl_xor(ps, off, 64);
        pd += __shfl_xor(pd, off, 64);
    }
    if (lane == 0) { al_s[node] = ps; al_d[node] = pd; }
}

// ---------------- softmax + aggregation (cooperative, 1x exp redundancy) ----------------

#define CH 64

template <bool ELU>
__global__ __launch_bounds__(256) void gat_aggregate_k(const float* __restrict__ h,
                                                       const float* __restrict__ al_s,
                                                       const float* __restrict__ al_d,
                                                       const int* __restrict__ row_ptr,
                                                       const int* __restrict__ srcs,
                                                       const float* __restrict__ bias,
                                                       float* __restrict__ out, int n) {
    __shared__ float w_lds[CH][8];
    __shared__ int   sc[CH];
    __shared__ float red[256];
    __shared__ float part[4][256];
    __shared__ float m_sh[8], inv_sh[8], ald_sh[8];

    int dst = blockIdx.x;
    int t = threadIdx.x;
    int beg = row_ptr[dst], end = row_ptr[dst + 1];
    int deg = end - beg;

    if (t < 8) ald_sh[t] = al_d[dst * 8 + t];
    __syncthreads();

    int hh = t & 7, e0 = t >> 3;
    float aldv = ald_sh[hh];

    float mp = -1e30f;
    for (int e = e0; e < deg; e += 32) {
        int s = srcs[beg + e];
        float l = al_s[s * 8 + hh] + aldv;
        l = (l > 0.f) ? l : NEG_SLOPE * l;
        mp = fmaxf(mp, l);
    }
    red[t] = mp;
    __syncthreads();
#pragma unroll
    for (int off = 128; off >= 8; off >>= 1) {
        if (t < off) red[t] = fmaxf(red[t], red[t + off]);
        __syncthreads();
    }
    if (t < 8) m_sh[t] = red[t];
    __syncthreads();
    float mh = m_sh[hh];

    int g = t >> 6, lane = t & 63;
    int hd = lane >> 3;
    float4 acc = make_float4(0.f, 0.f, 0.f, 0.f);
    float swp = 0.f;

    for (int c0 = 0; c0 < deg; c0 += CH) {
        int len = min(CH, deg - c0);
#pragma unroll
        for (int sl = 0; sl < 2; ++sl) {
            int ep = e0 + sl * 32;
            if (ep < len) {
                int s = srcs[beg + c0 + ep];
                if (hh == 0) sc[ep] = s;
                float l = al_s[s * 8 + hh] + aldv;
                l = (l > 0.f) ? l : NEG_SLOPE * l;
                float w = expf(l - mh);
                w_lds[ep][hh] = w;
                swp += w;
            }
        }
        __syncthreads();
        for (int e = g; e < len; e += 4) {
            float w = w_lds[e][hd];
            const float4* hp = reinterpret_cast<const float4*>(h + (size_t)sc[e] * 256);
            float4 v = hp[lane];
            acc.x = fmaf(w, v.x, acc.x);
            acc.y = fmaf(w, v.y, acc.y);
            acc.z = fmaf(w, v.z, acc.z);
            acc.w = fmaf(w, v.w, acc.w);
        }
        __syncthreads();
    }

    red[t] = swp;
    __syncthreads();
#pragma unroll
    for (int off = 128; off >= 8; off >>= 1) {
        if (t < off) red[t] += red[t + off];
        __syncthreads();
    }
    if (t < 8) inv_sh[t] = 1.f / (red[t] + 1e-16f);
    *reinterpret_cast<float4*>(&part[g][4 * lane]) = acc;
    __syncthreads();
    float tot = part[0][t] + part[1][t] + part[2][t] + part[3][t];
    float v = tot * inv_sh[t >> 5] + bias[t];
    if (ELU) v = (v > 0.f) ? v : expm1f(v);
    out[(size_t)dst * 256 + t] = v;
}

__global__ __launch_bounds__(64) void gat_aggregate3_k(const float* __restrict__ h,
                                                       const float* __restrict__ al_s,
                                                       const float* __restrict__ al_d,
                                                       const int* __restrict__ row_ptr,
                                                       const int* __restrict__ srcs,
                                                       const float* __restrict__ bias,
                                                       float* __restrict__ out, int n) {
    __shared__ float w_l[CH];
    __shared__ int   sc[CH];
    int dst = blockIdx.x;
    int lane = threadIdx.x;
    int beg = row_ptr[dst], end = row_ptr[dst + 1];
    int deg = end - beg;
    float ald = al_d[dst];

    float mp = -1e30f;
    for (int e = lane; e < deg; e += 64) {
        int s = srcs[beg + e];
        float l = al_s[s] + ald;
        l = (l > 0.f) ? l : NEG_SLOPE * l;
        mp = fmaxf(mp, l);
    }
#pragma unroll
    for (int off = 32; off; off >>= 1) mp = fmaxf(mp, __shfl_xor(mp, off, 64));

    float acc = 0.f, swp = 0.f;
    for (int c0 = 0; c0 < deg; c0 += CH) {
        int len = min(CH, deg - c0);
        if (lane < len) {
            int s = srcs[beg + c0 + lane];
            sc[lane] = s;
            float l = al_s[s] + ald;
            l = (l > 0.f) ? l : NEG_SLOPE * l;
            float w = expf(l - mp);
            w_l[lane] = w;
            swp += w;
        }
        __syncthreads();
        if (lane < 40) {
            for (int e = 0; e < len; ++e)
                acc = fmaf(w_l[e], h[(size_t)sc[e] * 40 + lane], acc);
        }
        __syncthreads();
    }
#pragma unroll
    for (int off = 32; off; off >>= 1) swp += __shfl_xor(swp, off, 64);
    if (lane < 40) out[(size_t)dst * 40 + lane] = acc / (swp + 1e-16f) + bias[lane];
}

// ---------------- launch ----------------

extern "C" void kernel_launch(void* const* d_in, const int* in_sizes, int n_in,
                              void* d_out, int out_size, void* d_ws, size_t ws_size,
                              hipStream_t stream) {
    const float* x   = (const float*)d_in[0];
    const int*   ei  = (const int*)d_in[1];
    const float* W1  = (const float*)d_in[2];
    const float* as1 = (const float*)d_in[3];
    const float* ad1 = (const float*)d_in[4];
    const float* b1  = (const float*)d_in[5];
    const float* W2  = (const float*)d_in[6];
    const float* as2 = (const float*)d_in[7];
    const float* ad2 = (const float*)d_in[8];
    const float* b2  = (const float*)d_in[9];
    const float* W3  = (const float*)d_in[10];
    const float* as3 = (const float*)d_in[11];
    const float* ad3 = (const float*)d_in[12];
    const float* b3  = (const float*)d_in[13];

    const int N = in_sizes[0] / 128;   // 50000
    const int E = in_sizes[1] / 2;     // 800000
    const int ET = E + N;

    char* ws = (char*)d_ws;
    size_t off = 0;
    auto alloc = [&](size_t bytes) -> void* {
        void* p = ws + off;
        off += (bytes + 255) & ~(size_t)255;
        return p;
    };
    int*   row_ptr = (int*)alloc(sizeof(int) * (N + 1));
    int*   pos     = (int*)alloc(sizeof(int) * N);
    int*   srcs    = (int*)alloc(sizeof(int) * ET);
    int*   bsums   = (int*)alloc(sizeof(int) * 64);
    float* als     = (float*)alloc(sizeof(float) * N * 8);
    float* ald     = (float*)alloc(sizeof(float) * N * 8);
    float* hbuf    = (float*)alloc(sizeof(float) * (size_t)N * 256);
    float* obuf    = (float*)alloc(sizeof(float) * (size_t)N * 256);
    unsigned short* wbh = (unsigned short*)alloc(sizeof(unsigned short) * 256 * 256);
    unsigned short* wbl = (unsigned short*)alloc(sizeof(unsigned short) * 256 * 256);
    (void)ws_size;

    const int nb = (N + 1023) / 1024;

    // --- CSR build ---
    hipMemsetAsync(pos, 0, sizeof(int) * N, stream);
    count_edges_k<<<(ET + 255) / 256, 256, 0, stream>>>(ei, E, N, pos);
    scan1_k<<<nb, 256, 0, stream>>>(pos, row_ptr, bsums, N);
    scan2_k<<<1, 64, 0, stream>>>(bsums, nb);
    scan3_k<<<(N + 1 + 255) / 256, 256, 0, stream>>>(row_ptr, pos, bsums, N, ET);
    scatter_edges_k<<<(ET + 255) / 256, 256, 0, stream>>>(ei, E, N, pos, srcs);

    const int gy = (N + 127) / 128;

    // --- layer 1: x[N,128] @ W1[128,256] (MFMA split-bf16) ---
    convert_w_k<<<(128 * 256 + 255) / 256, 256, 0, stream>>>(W1, wbh, wbl, 128, 256);
    mfma_gemm_k<<<dim3(2, gy), 256, 0, stream>>>(x, wbh, wbl, hbuf, N, 128, 256);
    compute_al_k<<<N, 256, 0, stream>>>(hbuf, as1, ad1, als, ald, N);
    gat_aggregate_k<true><<<N, 256, 0, stream>>>(hbuf, als, ald, row_ptr, srcs, b1, obuf, N);

    // --- layer 2: obuf[N,256] @ W2[256,256] (MFMA split-bf16) ---
    convert_w_k<<<(256 * 256 + 255) / 256, 256, 0, stream>>>(W2, wbh, wbl, 256, 256);
    mfma_gemm_k<<<dim3(2, gy), 256, 0, stream>>>(obuf, wbh, wbl, hbuf, N, 256, 256);
    compute_al_k<<<N, 256, 0, stream>>>(hbuf, as2, ad2, als, ald, N);
    gat_aggregate_k<true><<<N, 256, 0, stream>>>(hbuf, als, ald, row_ptr, srcs, b2, obuf, N);

    // --- layer 3: obuf[N,256] @ W3[256,40] (vector fp32) ---
    sgemm_k<<<dim3(1, (N + BM - 1) / BM), 256, 0, stream>>>(obuf, W3, hbuf, N, 256, 40);
    compute_al3_k<<<(N + 3) / 4, 256, 0, stream>>>(hbuf, as3, ad3, als, ald, N);
    gat_aggregate3_k<<<N, 64, 0, stream>>>(hbuf, als, ald, row_ptr, srcs, b3, (float*)d_out, N);
}

// Round 4
// 563.908 us; speedup vs baseline: 1.5346x; 1.0542x over previous
//
#include <hip/hip_runtime.h>
#include <hip/hip_bf16.h>

#define NEG_SLOPE 0.2f

typedef __attribute__((ext_vector_type(8))) short bf16x8;
typedef __attribute__((ext_vector_type(4))) float f32x4;

__device__ __forceinline__ unsigned short f2bf(float v) {
    union { float f; unsigned int u; } x; x.f = v;
    unsigned int r = x.u + 0x7fffu + ((x.u >> 16) & 1u);
    return (unsigned short)(r >> 16);
}
__device__ __forceinline__ float bf2f(unsigned short b) {
    union { unsigned int u; float f; } x; x.u = ((unsigned int)b) << 16;
    return x.f;
}

// ---------------- CSR build ----------------

__global__ void count_edges_k(const int* __restrict__ ei, int E, int n, int* __restrict__ cnt) {
    int e = blockIdx.x * 256 + threadIdx.x;
    int ET = E + n;
    if (e >= ET) return;
    int d = (e < E) ? ei[E + e] : (e - E);
    atomicAdd(&cnt[d], 1);
}

__global__ void scan1_k(const int* __restrict__ cnt, int* __restrict__ row_ptr,
                        int* __restrict__ bsums, int n) {
    __shared__ int sd[256];
    int b = blockIdx.x, t = threadIdx.x;
    int base = b * 1024 + t * 4;
    int v[4];
    int loc = 0;
#pragma unroll
    for (int j = 0; j < 4; ++j) {
        v[j] = (base + j < n) ? cnt[base + j] : 0;
        loc += v[j];
    }
    sd[t] = loc;
    __syncthreads();
    for (int off = 1; off < 256; off <<= 1) {
        int x = (t >= off) ? sd[t - off] : 0;
        __syncthreads();
        sd[t] += x;
        __syncthreads();
    }
    int run = sd[t] - loc;
    if (t == 255) bsums[b] = sd[t];
#pragma unroll
    for (int j = 0; j < 4; ++j) {
        if (base + j < n) row_ptr[base + j] = run;
        run += v[j];
    }
}

__global__ void scan2_k(int* __restrict__ bsums, int nb) {
    if (threadIdx.x == 0 && blockIdx.x == 0) {
        int run = 0;
        for (int i = 0; i < nb; ++i) { int x = bsums[i]; bsums[i] = run; run += x; }
    }
}

__global__ void scan3_k(int* __restrict__ row_ptr, int* __restrict__ pos,
                        const int* __restrict__ bsums, int n, int total) {
    int idx = blockIdx.x * 256 + threadIdx.x;
    if (idx < n) {
        int vv = row_ptr[idx] + bsums[idx >> 10];
        row_ptr[idx] = vv;
        pos[idx] = vv;
    } else if (idx == n) {
        row_ptr[n] = total;
    }
}

__global__ void scatter_edges_k(const int* __restrict__ ei, int E, int n,
                                int* __restrict__ pos, int* __restrict__ srcs) {
    int e = blockIdx.x * 256 + threadIdx.x;
    int ET = E + n;
    if (e >= ET) return;
    int s, d;
    if (e < E) { s = ei[e]; d = ei[E + e]; }
    else       { s = e - E; d = e - E; }
    int idx = atomicAdd(&pos[d], 1);
    srcs[idx] = s;
}

// ---------------- weight pre-convert: W[K][Nc] fp32 -> col-major hi/lo bf16 [Nc][K] ----------------

__global__ void convert_w_k(const float* __restrict__ W,
                            unsigned short* __restrict__ Bh, unsigned short* __restrict__ Bl,
                            int K, int Nc) {
    int idx = blockIdx.x * 256 + threadIdx.x;
    if (idx >= K * Nc) return;
    int k = idx / Nc, c = idx - k * Nc;
    float v = W[idx];
    unsigned short h = f2bf(v);
    float r = v - bf2f(h);
    Bh[c * K + k] = h;
    Bl[c * K + k] = f2bf(r);
}

// ---------------- split-bf16 MFMA GEMM -> bf16 output ----------------
// A fp32 row-major; W pre-converted Bh/Bl bf16 col-major [Nc][K]; C bf16 row-major.
// block = 256 thr (4 waves), tile 128x128, wave tile 64x64, K-step 32.

#define GPAD 40

__global__ __launch_bounds__(256) void mfma_gemm_k(const float* __restrict__ A,
                                                   const unsigned short* __restrict__ Bh,
                                                   const unsigned short* __restrict__ Bl,
                                                   unsigned short* __restrict__ Cb,
                                                   int M, int K, int Nc) {
    __shared__ unsigned short Ash[128][GPAD];
    __shared__ unsigned short Asl[128][GPAD];
    __shared__ unsigned short Bsh[128][GPAD];
    __shared__ unsigned short Bsl[128][GPAD];

    int bm = blockIdx.y * 128;
    int bn = blockIdx.x * 128;
    int t = threadIdx.x;
    int w = t >> 6, l = t & 63;
    int wm = w >> 1, wn = w & 1;
    int lr = l & 15, lk = (l >> 4) * 8;

    int srow = t >> 1;
    int skh  = (t & 1) * 16;

    f32x4 acc[4][4];
#pragma unroll
    for (int i = 0; i < 4; ++i)
#pragma unroll
        for (int j = 0; j < 4; ++j)
            acc[i][j] = (f32x4){0.f, 0.f, 0.f, 0.f};

    const int arow = bm + srow;
    const bool arow_ok = (arow < M);
    const size_t acol_base = (size_t)arow * K + skh;
    const size_t bcol_base = (size_t)(bn + srow) * K + skh;

    for (int k0 = 0; k0 < K; k0 += 32) {
        float vv[16];
        if (arow_ok) {
            const float4* ap = reinterpret_cast<const float4*>(A + acol_base + k0);
#pragma unroll
            for (int q = 0; q < 4; ++q) {
                float4 v4 = ap[q];
                vv[4 * q + 0] = v4.x; vv[4 * q + 1] = v4.y;
                vv[4 * q + 2] = v4.z; vv[4 * q + 3] = v4.w;
            }
        } else {
#pragma unroll
            for (int q = 0; q < 16; ++q) vv[q] = 0.f;
        }
        unsigned int hw[8], lw[8];
#pragma unroll
        for (int q = 0; q < 8; ++q) {
            unsigned short h0 = f2bf(vv[2 * q]);
            unsigned short h1 = f2bf(vv[2 * q + 1]);
            unsigned short l0 = f2bf(vv[2 * q] - bf2f(h0));
            unsigned short l1 = f2bf(vv[2 * q + 1] - bf2f(h1));
            hw[q] = (unsigned int)h0 | ((unsigned int)h1 << 16);
            lw[q] = (unsigned int)l0 | ((unsigned int)l1 << 16);
        }
        __syncthreads();
        {
            uint4* dh = reinterpret_cast<uint4*>(&Ash[srow][skh]);
            uint4* dl = reinterpret_cast<uint4*>(&Asl[srow][skh]);
            dh[0] = make_uint4(hw[0], hw[1], hw[2], hw[3]);
            dh[1] = make_uint4(hw[4], hw[5], hw[6], hw[7]);
            dl[0] = make_uint4(lw[0], lw[1], lw[2], lw[3]);
            dl[1] = make_uint4(lw[4], lw[5], lw[6], lw[7]);
        }
        {
            const uint4* sh = reinterpret_cast<const uint4*>(Bh + bcol_base + k0);
            const uint4* sl = reinterpret_cast<const uint4*>(Bl + bcol_base + k0);
            uint4* dh = reinterpret_cast<uint4*>(&Bsh[srow][skh]);
            uint4* dl = reinterpret_cast<uint4*>(&Bsl[srow][skh]);
            dh[0] = sh[0]; dh[1] = sh[1];
            dl[0] = sl[0]; dl[1] = sl[1];
        }
        __syncthreads();

        bf16x8 ah[4], al[4], bh[4], bl[4];
#pragma unroll
        for (int i = 0; i < 4; ++i) {
            int r = wm * 64 + i * 16 + lr;
            ah[i] = *reinterpret_cast<const bf16x8*>(&Ash[r][lk]);
            al[i] = *reinterpret_cast<const bf16x8*>(&Asl[r][lk]);
        }
#pragma unroll
        for (int j = 0; j < 4; ++j) {
            int c = wn * 64 + j * 16 + lr;
            bh[j] = *reinterpret_cast<const bf16x8*>(&Bsh[c][lk]);
            bl[j] = *reinterpret_cast<const bf16x8*>(&Bsl[c][lk]);
        }
#pragma unroll
        for (int i = 0; i < 4; ++i)
#pragma unroll
            for (int j = 0; j < 4; ++j) {
                acc[i][j] = __builtin_amdgcn_mfma_f32_16x16x32_bf16(ah[i], bh[j], acc[i][j], 0, 0, 0);
                acc[i][j] = __builtin_amdgcn_mfma_f32_16x16x32_bf16(ah[i], bl[j], acc[i][j], 0, 0, 0);
                acc[i][j] = __builtin_amdgcn_mfma_f32_16x16x32_bf16(al[i], bh[j], acc[i][j], 0, 0, 0);
            }
    }

    // D mapping: col = lane&15, row = (lane>>4)*4 + reg
#pragma unroll
    for (int i = 0; i < 4; ++i) {
#pragma unroll
        for (int r = 0; r < 4; ++r) {
            int row_g = bm + wm * 64 + i * 16 + (l >> 4) * 4 + r;
            if (row_g >= M) continue;
#pragma unroll
            for (int j = 0; j < 4; ++j) {
                int col_g = bn + wn * 64 + j * 16 + lr;
                Cb[(size_t)row_g * Nc + col_g] = f2bf(acc[i][j][r]);
            }
        }
    }
}

// ---------------- fp32 GEMM (layer 3 only, Nc=40) -> bf16 output ----------------

#define BM 64
#define BN 64
#define BKK 16

__global__ __launch_bounds__(256) void sgemm_k(const float* __restrict__ A,
                                               const float* __restrict__ B,
                                               unsigned short* __restrict__ Cb,
                                               int M, int K, int Nc) {
    __shared__ float As[BKK][BM + 4];
    __shared__ float Bs[BKK][BN + 4];
    int bm = blockIdx.y * BM, bn = blockIdx.x * BN;
    int t = threadIdx.x;
    int tx = t & 15, ty = t >> 4;
    float acc[4][4] = {};
    for (int k0 = 0; k0 < K; k0 += BKK) {
        {
            int row = t >> 2, kq = (t & 3) * 4;
            int r = bm + row;
            float4 v = make_float4(0.f, 0.f, 0.f, 0.f);
            if (r < M) v = *reinterpret_cast<const float4*>(A + (size_t)r * K + k0 + kq);
            As[kq + 0][row] = v.x; As[kq + 1][row] = v.y;
            As[kq + 2][row] = v.z; As[kq + 3][row] = v.w;
        }
        {
            int krow = t >> 4, nq = (t & 15) * 4;
            int col = bn + nq;
            float4 v = make_float4(0.f, 0.f, 0.f, 0.f);
            if (col < Nc) v = *reinterpret_cast<const float4*>(B + (size_t)(k0 + krow) * Nc + col);
            Bs[krow][nq + 0] = v.x; Bs[krow][nq + 1] = v.y;
            Bs[krow][nq + 2] = v.z; Bs[krow][nq + 3] = v.w;
        }
        __syncthreads();
#pragma unroll
        for (int k = 0; k < BKK; ++k) {
            float a[4], b[4];
#pragma unroll
            for (int i = 0; i < 4; ++i) a[i] = As[k][ty * 4 + i];
#pragma unroll
            for (int j = 0; j < 4; ++j) b[j] = Bs[k][tx * 4 + j];
#pragma unroll
            for (int i = 0; i < 4; ++i)
#pragma unroll
                for (int j = 0; j < 4; ++j)
                    acc[i][j] = fmaf(a[i], b[j], acc[i][j]);
        }
        __syncthreads();
    }
#pragma unroll
    for (int i = 0; i < 4; ++i) {
        int r = bm + ty * 4 + i;
        if (r >= M) continue;
#pragma unroll
        for (int j = 0; j < 4; ++j) {
            int c = bn + tx * 4 + j;
            if (c < Nc) Cb[(size_t)r * Nc + c] = f2bf(acc[i][j]);
        }
    }
}

// ---------------- attention logit precompute (bf16 h) ----------------

__global__ void compute_al_k(const unsigned short* __restrict__ h,
                             const float* __restrict__ a_src, const float* __restrict__ a_dst,
                             float* __restrict__ al_s, float* __restrict__ al_d, int n) {
    int node = blockIdx.x;
    int t = threadIdx.x;
    int hd = t >> 5, d = t & 31;
    float hv = bf2f(h[(size_t)node * 256 + t]);
    float ps = hv * a_src[t];
    float pd = hv * a_dst[t];
#pragma unroll
    for (int off = 16; off; off >>= 1) {
        ps += __shfl_xor(ps, off, 32);
        pd += __shfl_xor(pd, off, 32);
    }
    if (d == 0) {
        al_s[node * 8 + hd] = ps;
        al_d[node * 8 + hd] = pd;
    }
}

__global__ void compute_al3_k(const unsigned short* __restrict__ h,
                              const float* __restrict__ a_src, const float* __restrict__ a_dst,
                              float* __restrict__ al_s, float* __restrict__ al_d, int n) {
    int wid = threadIdx.x >> 6, lane = threadIdx.x & 63;
    int node = blockIdx.x * 4 + wid;
    if (node >= n) return;
    float hv = (lane < 40) ? bf2f(h[(size_t)node * 40 + lane]) : 0.f;
    float ps = (lane < 40) ? hv * a_src[lane] : 0.f;
    float pd = (lane < 40) ? hv * a_dst[lane] : 0.f;
#pragma unroll
    for (int off = 32; off; off >>= 1) {
        ps += __shfl_xor(ps, off, 64);
        pd += __shfl_xor(pd, off, 64);
    }
    if (lane == 0) { al_s[node] = ps; al_d[node] = pd; }
}

// ---------------- softmax + aggregation (bf16 gather, fp32 accumulate) ----------------

#define CH 64

template <bool ELU>
__global__ __launch_bounds__(256) void gat_aggregate_k(const unsigned short* __restrict__ h,
                                                       const float* __restrict__ al_s,
                                                       const float* __restrict__ al_d,
                                                       const int* __restrict__ row_ptr,
                                                       const int* __restrict__ srcs,
                                                       const float* __restrict__ bias,
                                                       float* __restrict__ out, int n) {
    __shared__ float w_lds[CH][8];
    __shared__ int   sc[CH];
    __shared__ float red[256];
    __shared__ float part[4][256];
    __shared__ float m_sh[8], inv_sh[8], ald_sh[8];

    int dst = blockIdx.x;
    int t = threadIdx.x;
    int beg = row_ptr[dst], end = row_ptr[dst + 1];
    int deg = end - beg;

    if (t < 8) ald_sh[t] = al_d[dst * 8 + t];
    __syncthreads();

    int hh = t & 7, e0 = t >> 3;
    float aldv = ald_sh[hh];

    // pass 1: per-head max
    float mp = -1e30f;
    for (int e = e0; e < deg; e += 32) {
        int s = srcs[beg + e];
        float l = al_s[s * 8 + hh] + aldv;
        l = (l > 0.f) ? l : NEG_SLOPE * l;
        mp = fmaxf(mp, l);
    }
    red[t] = mp;
    __syncthreads();
#pragma unroll
    for (int off = 128; off >= 8; off >>= 1) {
        if (t < off) red[t] = fmaxf(red[t], red[t + off]);
        __syncthreads();
    }
    if (t < 8) m_sh[t] = red[t];
    __syncthreads();
    float mh = m_sh[hh];

    int g = t >> 6, lane = t & 63;
    int hd = lane >> 3;
    float4 acc = make_float4(0.f, 0.f, 0.f, 0.f);
    float swp = 0.f;

    for (int c0 = 0; c0 < deg; c0 += CH) {
        int len = min(CH, deg - c0);
#pragma unroll
        for (int sl = 0; sl < 2; ++sl) {
            int ep = e0 + sl * 32;
            if (ep < len) {
                int s = srcs[beg + c0 + ep];
                if (hh == 0) sc[ep] = s;
                float l = al_s[s * 8 + hh] + aldv;
                l = (l > 0.f) ? l : NEG_SLOPE * l;
                float w = expf(l - mh);
                w_lds[ep][hh] = w;
                swp += w;
            }
        }
        __syncthreads();
        // phase B: bf16 gather, 4 cols (8 B) per lane
        for (int e = g; e < len; e += 4) {
            float w = w_lds[e][hd];
            const ushort4* hp = reinterpret_cast<const ushort4*>(h + (size_t)sc[e] * 256);
            ushort4 v = hp[lane];
            acc.x = fmaf(w, bf2f(v.x), acc.x);
            acc.y = fmaf(w, bf2f(v.y), acc.y);
            acc.z = fmaf(w, bf2f(v.z), acc.z);
            acc.w = fmaf(w, bf2f(v.w), acc.w);
        }
        __syncthreads();
    }

    red[t] = swp;
    __syncthreads();
#pragma unroll
    for (int off = 128; off >= 8; off >>= 1) {
        if (t < off) red[t] += red[t + off];
        __syncthreads();
    }
    if (t < 8) inv_sh[t] = 1.f / (red[t] + 1e-16f);
    *reinterpret_cast<float4*>(&part[g][4 * lane]) = acc;
    __syncthreads();
    float tot = part[0][t] + part[1][t] + part[2][t] + part[3][t];
    float v = tot * inv_sh[t >> 5] + bias[t];
    if (ELU) v = (v > 0.f) ? v : expm1f(v);
    out[(size_t)dst * 256 + t] = v;
}

__global__ __launch_bounds__(64) void gat_aggregate3_k(const unsigned short* __restrict__ h,
                                                       const float* __restrict__ al_s,
                                                       const float* __restrict__ al_d,
                                                       const int* __restrict__ row_ptr,
                                                       const int* __restrict__ srcs,
                                                       const float* __restrict__ bias,
                                                       float* __restrict__ out, int n) {
    __shared__ float w_l[CH];
    __shared__ int   sc[CH];
    int dst = blockIdx.x;
    int lane = threadIdx.x;
    int beg = row_ptr[dst], end = row_ptr[dst + 1];
    int deg = end - beg;
    float ald = al_d[dst];

    float mp = -1e30f;
    for (int e = lane; e < deg; e += 64) {
        int s = srcs[beg + e];
        float l = al_s[s] + ald;
        l = (l > 0.f) ? l : NEG_SLOPE * l;
        mp = fmaxf(mp, l);
    }
#pragma unroll
    for (int off = 32; off; off >>= 1) mp = fmaxf(mp, __shfl_xor(mp, off, 64));

    float acc = 0.f, swp = 0.f;
    for (int c0 = 0; c0 < deg; c0 += CH) {
        int len = min(CH, deg - c0);
        if (lane < len) {
            int s = srcs[beg + c0 + lane];
            sc[lane] = s;
            float l = al_s[s] + ald;
            l = (l > 0.f) ? l : NEG_SLOPE * l;
            float w = expf(l - mp);
            w_l[lane] = w;
            swp += w;
        }
        __syncthreads();
        if (lane < 40) {
            for (int e = 0; e < len; ++e)
                acc = fmaf(w_l[e], bf2f(h[(size_t)sc[e] * 40 + lane]), acc);
        }
        __syncthreads();
    }
#pragma unroll
    for (int off = 32; off; off >>= 1) swp += __shfl_xor(swp, off, 64);
    if (lane < 40) out[(size_t)dst * 40 + lane] = acc / (swp + 1e-16f) + bias[lane];
}

// ---------------- launch ----------------

extern "C" void kernel_launch(void* const* d_in, const int* in_sizes, int n_in,
                              void* d_out, int out_size, void* d_ws, size_t ws_size,
                              hipStream_t stream) {
    const float* x   = (const float*)d_in[0];
    const int*   ei  = (const int*)d_in[1];
    const float* W1  = (const float*)d_in[2];
    const float* as1 = (const float*)d_in[3];
    const float* ad1 = (const float*)d_in[4];
    const float* b1  = (const float*)d_in[5];
    const float* W2  = (const float*)d_in[6];
    const float* as2 = (const float*)d_in[7];
    const float* ad2 = (const float*)d_in[8];
    const float* b2  = (const float*)d_in[9];
    const float* W3  = (const float*)d_in[10];
    const float* as3 = (const float*)d_in[11];
    const float* ad3 = (const float*)d_in[12];
    const float* b3  = (const float*)d_in[13];

    const int N = in_sizes[0] / 128;   // 50000
    const int E = in_sizes[1] / 2;     // 800000
    const int ET = E + N;

    char* ws = (char*)d_ws;
    size_t off = 0;
    auto alloc = [&](size_t bytes) -> void* {
        void* p = ws + off;
        off += (bytes + 255) & ~(size_t)255;
        return p;
    };
    int*   row_ptr = (int*)alloc(sizeof(int) * (N + 1));
    int*   pos     = (int*)alloc(sizeof(int) * N);
    int*   srcs    = (int*)alloc(sizeof(int) * ET);
    int*   bsums   = (int*)alloc(sizeof(int) * 64);
    float* als     = (float*)alloc(sizeof(float) * N * 8);
    float* ald     = (float*)alloc(sizeof(float) * N * 8);
    unsigned short* hb16 = (unsigned short*)alloc(sizeof(unsigned short) * (size_t)N * 256);
    float* obuf    = (float*)alloc(sizeof(float) * (size_t)N * 256);
    unsigned short* wbh = (unsigned short*)alloc(sizeof(unsigned short) * 256 * 256);
    unsigned short* wbl = (unsigned short*)alloc(sizeof(unsigned short) * 256 * 256);
    (void)ws_size;

    const int nb = (N + 1023) / 1024;

    // --- CSR build ---
    hipMemsetAsync(pos, 0, sizeof(int) * N, stream);
    count_edges_k<<<(ET + 255) / 256, 256, 0, stream>>>(ei, E, N, pos);
    scan1_k<<<nb, 256, 0, stream>>>(pos, row_ptr, bsums, N);
    scan2_k<<<1, 64, 0, stream>>>(bsums, nb);
    scan3_k<<<(N + 1 + 255) / 256, 256, 0, stream>>>(row_ptr, pos, bsums, N, ET);
    scatter_edges_k<<<(ET + 255) / 256, 256, 0, stream>>>(ei, E, N, pos, srcs);

    const int gy = (N + 127) / 128;

    // --- layer 1: x[N,128] @ W1[128,256] (MFMA split-bf16 -> bf16 h) ---
    convert_w_k<<<(128 * 256 + 255) / 256, 256, 0, stream>>>(W1, wbh, wbl, 128, 256);
    mfma_gemm_k<<<dim3(2, gy), 256, 0, stream>>>(x, wbh, wbl, hb16, N, 128, 256);
    compute_al_k<<<N, 256, 0, stream>>>(hb16, as1, ad1, als, ald, N);
    gat_aggregate_k<true><<<N, 256, 0, stream>>>(hb16, als, ald, row_ptr, srcs, b1, obuf, N);

    // --- layer 2: obuf[N,256] @ W2[256,256] ---
    convert_w_k<<<(256 * 256 + 255) / 256, 256, 0, stream>>>(W2, wbh, wbl, 256, 256);
    mfma_gemm_k<<<dim3(2, gy), 256, 0, stream>>>(obuf, wbh, wbl, hb16, N, 256, 256);
    compute_al_k<<<N, 256, 0, stream>>>(hb16, as2, ad2, als, ald, N);
    gat_aggregate_k<true><<<N, 256, 0, stream>>>(hb16, als, ald, row_ptr, srcs, b2, obuf, N);

    // --- layer 3: obuf[N,256] @ W3[256,40] (vector fp32 -> bf16 h3) ---
    sgemm_k<<<dim3(1, (N + BM - 1) / BM), 256, 0, stream>>>(obuf, W3, hb16, N, 256, 40);
    compute_al3_k<<<(N + 3) / 4, 256, 0, stream>>>(hb16, as3, ad3, als, ald, N);
    gat_aggregate3_k<<<N, 64, 0, stream>>>(hb16, als, ald, row_ptr, srcs, b3, (float*)d_out, N);
}